// Round 16
// baseline (146.924 us; speedup 1.0000x reference)
//
#include <hip/hip_runtime.h>
#include <math.h>

#define NN   50000
#define NE   1600000
#define FIN  512
#define H1F  128
#define NBUK  391    // ceil(NN/128)  — dst-bucket = 128 consecutive nodes
#define BIN_EPB 4096 // edges per binning block (16 per thread)
#define NBIN  391    // ceil(NE/BIN_EPB)

typedef __attribute__((ext_vector_type(8))) short bf16x8;
typedef __attribute__((ext_vector_type(4))) float f32x4;
typedef __attribute__((ext_vector_type(2))) float f32x2;

// ---------------- bf16 helpers ----------------
__device__ __forceinline__ float bflo(unsigned v) { return __uint_as_float(v << 16); }
__device__ __forceinline__ float bfhi(unsigned v) { return __uint_as_float(v & 0xffff0000u); }
__device__ __forceinline__ unsigned short f2bf(float f) {
  unsigned u = __float_as_uint(f);
  u += 0x7fffu + ((u >> 16) & 1u);   // round-to-nearest-even
  return (unsigned short)(u >> 16);
}
__device__ __forceinline__ unsigned pack2bf(float a, float b) {
  return (unsigned)f2bf(a) | ((unsigned)f2bf(b) << 16);
}

// ---------------- fp8 e4m3fn codec: HW cvt if available, SW fallback ----------------
#if defined(__has_builtin)
#  if __has_builtin(__builtin_amdgcn_cvt_pk_f32_fp8) && __has_builtin(__builtin_amdgcn_cvt_pk_fp8_f32)
#    define HW_FP8 1
#  endif
#endif
#ifndef HW_FP8
#  define HW_FP8 0
#endif

__device__ __forceinline__ float fp8dec_sw(unsigned v, int sh) {
  unsigned b = (v >> sh) & 0xffu;
  unsigned bits = ((b & 0x80u) << 24) | ((b & 0x7fu) << 20);
  return __uint_as_float(bits) * 0x1.0p+120f;
}
__device__ __forceinline__ unsigned fp8enc_sw(float f) {
  unsigned u = __float_as_uint(f * 0x1.0p-120f);
  unsigned s = (u >> 24) & 0x80u;
  u &= 0x7fffffffu;
  u += 0x7ffffu + ((u >> 20) & 1u);
  unsigned e = u >> 20;
  if (e > 0x7fu) e = 0x7fu;
  return s | e;
}

// decode 4 packed fp8 -> two f32x2 (feeds v_pk_add_f32 directly)
__device__ __forceinline__ void fp8dec4p(unsigned v, f32x2& lo, f32x2& hi) {
#if HW_FP8
  lo = __builtin_amdgcn_cvt_pk_f32_fp8(v, false);   // bytes 0,1
  hi = __builtin_amdgcn_cvt_pk_f32_fp8(v, true);    // bytes 2,3
#else
  lo = (f32x2){fp8dec_sw(v, 0), fp8dec_sw(v, 8)};
  hi = (f32x2){fp8dec_sw(v, 16), fp8dec_sw(v, 24)};
#endif
}
__device__ __forceinline__ unsigned fp8enc4(float a, float b, float c, float d) {
#if HW_FP8
  unsigned r = (unsigned)__builtin_amdgcn_cvt_pk_fp8_f32(a, b, 0, false);
  r = (unsigned)__builtin_amdgcn_cvt_pk_fp8_f32(c, d, (int)r, true);
  return r;
#else
  return fp8enc_sw(a) | (fp8enc_sw(b) << 8) | (fp8enc_sw(c) << 16) | (fp8enc_sw(d) << 24);
#endif
}

// ---------------- CSR build: radix partition, ZERO global atomics ----------------

__global__ __launch_bounds__(256) void k_binhist(const int* __restrict__ ei,
                                                 int* __restrict__ gh) {
  __shared__ int hist[NBUK];
  int t  = threadIdx.x;
  int e0 = blockIdx.x * BIN_EPB;
  for (int b = t; b < NBUK; b += 256) hist[b] = 0;
  __syncthreads();
#pragma unroll
  for (int j = 0; j < 16; ++j) {
    int e = e0 + j * 256 + t;
    if (e < NE) atomicAdd(&hist[ei[NE + e] >> 7], 1);
  }
  __syncthreads();
  for (int b = t; b < NBUK; b += 256) gh[(size_t)b * NBIN + blockIdx.x] = hist[b];
}

__global__ __launch_bounds__(64) void k_rowscan(int* __restrict__ gh,
                                                int* __restrict__ btot) {
  int row  = blockIdx.x;
  int lane = threadIdx.x;
  int* g = gh + (size_t)row * NBIN;
  int carry = 0;
  for (int c = 0; c < (NBIN + 63) / 64; ++c) {
    int idx = c * 64 + lane;
    int v = (idx < NBIN) ? g[idx] : 0;
    int incl = v;
#pragma unroll
    for (int off = 1; off < 64; off <<= 1) {
      int u = __shfl_up(incl, off, 64);
      if (lane >= off) incl += u;
    }
    if (idx < NBIN) g[idx] = carry + (incl - v);
    carry += __shfl(incl, 63, 64);
  }
  if (lane == 0) btot[row] = carry;
}

__global__ __launch_bounds__(512) void k_bscan(const int* __restrict__ btot,
                                               int* __restrict__ bbase) {
  __shared__ int ts[512];
  int t = threadIdx.x;
  int v = (t < NBUK) ? btot[t] : 0;
  ts[t] = v;
  __syncthreads();
  for (int off = 1; off < 512; off <<= 1) {
    int val = ts[t];
    int add = (t >= off) ? ts[t - off] : 0;
    __syncthreads();
    ts[t] = val + add;
    __syncthreads();
  }
  if (t < NBUK) bbase[t] = ts[t] - v;
  if (t == NBUK - 1) bbase[NBUK] = ts[t];   // == NE
}

__global__ __launch_bounds__(256) void k_binscat(const int* __restrict__ ei,
                                                 const int* __restrict__ gh,
                                                 const int* __restrict__ bbase,
                                                 unsigned* __restrict__ tmp) {
  __shared__ int hist[NBUK];
  __shared__ int sbase[NBUK];
  int t  = threadIdx.x;
  int e0 = blockIdx.x * BIN_EPB;
  for (int b = t; b < NBUK; b += 256) hist[b] = 0;
  __syncthreads();

  unsigned short d16[16];
  unsigned short p16[16];
#pragma unroll
  for (int j = 0; j < 16; ++j) {
    int e = e0 + j * 256 + t;
    d16[j] = 0xFFFFu;
    if (e < NE) {
      int d = ei[NE + e];
      d16[j] = (unsigned short)d;
      p16[j] = (unsigned short)atomicAdd(&hist[d >> 7], 1);
    }
  }
  __syncthreads();
  for (int b = t; b < NBUK; b += 256)
    sbase[b] = bbase[b] + gh[(size_t)b * NBIN + blockIdx.x];
  __syncthreads();
#pragma unroll
  for (int j = 0; j < 16; ++j) {
    int e = e0 + j * 256 + t;
    if (e < NE) {
      int s = ei[e];
      int d = (int)d16[j];
      tmp[sbase[d >> 7] + (int)p16[j]] = ((unsigned)s << 16) | (unsigned)d;
    }
  }
}

__global__ __launch_bounds__(256) void k_fill2x(const unsigned* __restrict__ tmp,
                                                const int* __restrict__ bbase,
                                                int* __restrict__ rowptr,
                                                float* __restrict__ dinv,
                                                int* __restrict__ csr) {
  __shared__ int cnt[128];
  __shared__ int lofs[128];
  __shared__ int cur[128];
  __shared__ int ts[256];
  int b  = blockIdx.x;
  int t  = threadIdx.x;
  int n0 = b << 7;
  int beg = bbase[b];
  int end = bbase[b + 1];
  if (t < 128) { cnt[t] = 0; cur[t] = 0; }
  __syncthreads();
  for (int i = beg + t; i < end; i += 256)
    atomicAdd(&cnt[tmp[i] & 127u], 1);   // d - n0 == d & 127
  __syncthreads();
  int v = (t < 128) ? cnt[t] : 0;
  ts[t] = v;
  __syncthreads();
  for (int off = 1; off < 128; off <<= 1) {
    int val = ts[t];
    int add = (t >= off) ? ts[t - off] : 0;
    __syncthreads();
    ts[t] = val + add;
    __syncthreads();
  }
  if (t < 128) {
    int excl = ts[t] - v;
    lofs[t] = beg + excl;
    int n = n0 + t;
    if (n < NN) {
      rowptr[n] = beg + excl;
      dinv[n]   = rsqrtf((float)(v + 1));   // self-loop included
    }
  }
  if (b == NBUK - 1 && t == 0) rowptr[NN] = end;
  __syncthreads();
  for (int i = beg + t; i < end; i += 256) {
    unsigned pk = tmp[i];
    int dl = (int)(pk & 127u);
    int s  = (int)(pk >> 16);
    int p  = atomicAdd(&cur[dl], 1);
    csr[lofs[dl] + p] = s;
  }
}

// ---------------- weight repack: fragment-order bf16 ----------------

__global__ __launch_bounds__(256) void k_cvtw1f(const float* __restrict__ W,
                                                unsigned short* __restrict__ W1f) {
  int i = blockIdx.x * 256 + threadIdx.x;   // 8192 chunks
  if (i >= 16 * 8 * 64) return;
  int s = i >> 9, rem = i & 511, f = rem >> 6, lane = rem & 63;
  int row = f * 16 + (lane & 15);
  int kb  = s * 32 + (lane >> 4) * 8;
  unsigned short c8[8];
#pragma unroll
  for (int j = 0; j < 8; ++j) c8[j] = f2bf(W[(size_t)(kb + j) * H1F + row]);
  *(uint4*)&W1f[(size_t)i * 8] = *(uint4*)c8;
}

// W23f interleaved for 2x2 wave split: col-block pairs [W2lo, W3lo, W2hi, W3hi].
__global__ __launch_bounds__(256) void k_cvtw23f(const float* __restrict__ W2,
                                                 const float* __restrict__ W3,
                                                 unsigned short* __restrict__ Wf) {
  int i = blockIdx.x * 256 + threadIdx.x;   // 2048 chunks
  if (i >= 4 * 8 * 64) return;
  int s = i >> 9, rem = i & 511, f = rem >> 6, lane = rem & 63;
  int row = f * 16 + (lane & 15);
  int kb  = s * 32 + (lane >> 4) * 8;
  int pair = row >> 5;
  const float* Wsrc = (pair & 1) ? W3 : W2;
  int c = (pair >> 1) * 32 + (row & 31);
  unsigned short c8[8];
#pragma unroll
  for (int j = 0; j < 8; ++j) c8[j] = f2bf(Wsrc[(size_t)(kb + j) * 64 + c]);
  *(uint4*)&Wf[(size_t)i * 8] = *(uint4*)c8;
}

// ---------------- GEMM1 (MFMA, 2x2 wave split): table1 = fp8(dinv * (x @ W1)) ----------------

#define G1_ABUF 5120                  // 64 rows * 80B
#define G1_BBUF 8192                  // 512 chunks * 16B
#define G1_BUF  (G1_ABUF + G1_BBUF)
#define G1_NSTEP 16

__global__ __launch_bounds__(256) void k_gemm1m(const float* __restrict__ X,
                                                const uint4* __restrict__ W1fv,
                                                const float* __restrict__ dinv,
                                                unsigned* __restrict__ out8) {
  __shared__ char lds[2 * G1_BUF];
  int tid  = threadIdx.x;
  int row0 = blockIdx.x * 64;
  int w    = tid >> 6;
  int wr   = w >> 1, wc = w & 1;
  int lane = tid & 63;

  int ar = tid >> 2, aq = tid & 3;        // A: row ar, k-chunk aq (8 floats)

  float4 av0, av1;
  uint4  bu0, bu1;

  auto load_g = [&](int s) {
    int k0 = s * 32;
    int row = row0 + ar;
    av0 = make_float4(0.f, 0.f, 0.f, 0.f);
    av1 = av0;
    if (row < NN) {
      const float* gp = X + (size_t)row * FIN + k0 + aq * 8;
      av0 = *(const float4*)gp;
      av1 = *(const float4*)(gp + 4);
    }
    const uint4* bp = W1fv + (size_t)s * 512;
    bu0 = bp[tid];
    bu1 = bp[tid + 256];
  };
  auto store_l = [&](int buf) {
    char* Ab = lds + buf * G1_BUF;
    char* Bb = Ab + G1_ABUF;
    uint4 ap;
    ap.x = pack2bf(av0.x, av0.y); ap.y = pack2bf(av0.z, av0.w);
    ap.z = pack2bf(av1.x, av1.y); ap.w = pack2bf(av1.z, av1.w);
    *(uint4*)(Ab + ar * 80 + aq * 16) = ap;
    *(uint4*)(Bb + tid * 16)        = bu0;   // linear -> conflict-free
    *(uint4*)(Bb + tid * 16 + 4096) = bu1;
  };

  f32x4 acc[2][4];
#pragma unroll
  for (int u = 0; u < 2; ++u)
#pragma unroll
    for (int f = 0; f < 4; ++f) acc[u][f] = (f32x4){0.f, 0.f, 0.f, 0.f};

  load_g(0);
  store_l(0);

  for (int s = 0; s < G1_NSTEP; ++s) {
    if (s + 1 < G1_NSTEP) load_g(s + 1);
    __syncthreads();
    const char* Ab = lds + (s & 1) * G1_BUF;
    const char* Bb = Ab + G1_ABUF;
    bf16x8 xa0 = *(const bf16x8*)(Ab + (wr * 32 + (lane & 15)) * 80 + (lane >> 4) * 16);
    bf16x8 xa1 = *(const bf16x8*)(Ab + (wr * 32 + 16 + (lane & 15)) * 80 + (lane >> 4) * 16);
#pragma unroll
    for (int f = 0; f < 4; ++f) {
      bf16x8 bt = *(const bf16x8*)(Bb + (wc * 4 + f) * 1024 + lane * 16);
      acc[0][f] = __builtin_amdgcn_mfma_f32_16x16x32_bf16(bt, xa0, acc[0][f], 0, 0, 0);
      acc[1][f] = __builtin_amdgcn_mfma_f32_16x16x32_bf16(bt, xa1, acc[1][f], 0, 0, 0);
    }
    if (s + 1 < G1_NSTEP) store_l((s + 1) & 1);
  }

#pragma unroll
  for (int u = 0; u < 2; ++u) {
    int orow = row0 + wr * 32 + u * 16 + (lane & 15);
    if (orow < NN) {
      float di = dinv[orow];                // pre-scale: table1 = dinv * hw1
      size_t base = (size_t)orow * 32;      // 32 uints = 128 fp8 per row
#pragma unroll
      for (int f = 0; f < 4; ++f) {
        int col = (wc * 4 + f) * 16 + (lane >> 4) * 4;
        out8[base + (col >> 2)] = fp8enc4(di * acc[u][f][0], di * acc[u][f][1],
                                          di * acc[u][f][2], di * acc[u][f][3]);
      }
    }
  }
}

// ---------------- aggregation over PRE-SCALED fp8 table ----------------
// ONE WAVE per dst node; 4 groups of 16 lanes = 4 edge slots per load.
// Lane loads uint2 (8B): 16 lanes x 8B = full 128B fp8 row; one wave-load
// fetches 4 edge rows (512B) -> ~3 wave-inst/edge, no degree-pair divergence.
// ALL __shfl are wave-uniform (hoisted out of divergent branches): on CDNA
// ds_bpermute from an EXEC-masked-off source lane is undefined — R14's bug.
// table[s] = dinv[s]*h[s]; out[d] = dinv[d]*(Σ table[s] + table[d]) (+bias)

template<bool BIAS, bool OUTBF>
__global__ __launch_bounds__(256) void k_agg8(const unsigned* __restrict__ feat,   // [NN][32] uints
                                              const int* __restrict__ rowptr,
                                              const int* __restrict__ csr,
                                              const float* __restrict__ dinv,
                                              const float* __restrict__ bias,
                                              void* __restrict__ out) {
  int gw   = (blockIdx.x * 256 + threadIdx.x) >> 6;   // one wave per dst
  int lane = threadIdx.x & 63;
  if (gw >= NN) return;
  int g  = lane >> 4;          // edge-slot group 0..3
  int sl = lane & 15;          // sublane: feats sl*8 .. sl*8+7
  int beg = rowptr[gw], end = rowptr[gw + 1];
  float di = dinv[gw];
  f32x2 acc0 = (f32x2){0.f, 0.f}, acc1 = (f32x2){0.f, 0.f};
  f32x2 acc2 = (f32x2){0.f, 0.f}, acc3 = (f32x2){0.f, 0.f};

  for (int e = beg; e < end; e += 64) {
    int cnt = end - e; if (cnt > 64) cnt = 64;
    int sv = 0;
    if (lane < cnt) sv = csr[e + lane];
    int j = 0;
    for (; j + 8 <= cnt; j += 8) {
      // wave-uniform trip count: all 64 lanes active at every __shfl below
      int s0 = __shfl(sv, j + g, 64);
      int s1 = __shfl(sv, j + 4 + g, 64);
      uint2 v0 = *(const uint2*)&feat[(size_t)s0 * 32 + sl * 2];
      uint2 v1 = *(const uint2*)&feat[(size_t)s1 * 32 + sl * 2];
      f32x2 lo, hi;
      fp8dec4p(v0.x, lo, hi); acc0 += lo; acc1 += hi;
      fp8dec4p(v0.y, lo, hi); acc2 += lo; acc3 += hi;
      fp8dec4p(v1.x, lo, hi); acc0 += lo; acc1 += hi;
      fp8dec4p(v1.y, lo, hi); acc2 += lo; acc3 += hi;
    }
    for (; j < cnt; j += 4) {
      int idx  = j + g;
      int srcl = (idx < cnt) ? idx : 0;       // clamp source lane
      int s = __shfl(sv, srcl, 64);           // executed by ALL lanes (uniform)
      if (idx < cnt) {                        // only load/accumulate diverges
        uint2 v = *(const uint2*)&feat[(size_t)s * 32 + sl * 2];
        f32x2 lo, hi;
        fp8dec4p(v.x, lo, hi); acc0 += lo; acc1 += hi;
        fp8dec4p(v.y, lo, hi); acc2 += lo; acc3 += hi;
      }
    }
  }
  // self loop (group 0 only, counted once): table[d] already dinv[d]*h[d]
  if (g == 0) {
    uint2 v = *(const uint2*)&feat[(size_t)gw * 32 + sl * 2];
    f32x2 lo, hi;
    fp8dec4p(v.x, lo, hi); acc0 += lo; acc1 += hi;
    fp8dec4p(v.y, lo, hi); acc2 += lo; acc3 += hi;
  }
  // fold the 4 groups (xor 16, then 32) — all lanes active
#pragma unroll
  for (int d = 16; d <= 32; d <<= 1) {
    f32x2 t0, t1, t2, t3;
    t0[0] = __shfl_xor(acc0[0], d, 64); t0[1] = __shfl_xor(acc0[1], d, 64);
    t1[0] = __shfl_xor(acc1[0], d, 64); t1[1] = __shfl_xor(acc1[1], d, 64);
    t2[0] = __shfl_xor(acc2[0], d, 64); t2[1] = __shfl_xor(acc2[1], d, 64);
    t3[0] = __shfl_xor(acc3[0], d, 64); t3[1] = __shfl_xor(acc3[1], d, 64);
    acc0 += t0; acc1 += t1; acc2 += t2; acc3 += t3;
  }
  float a0 = di * acc0[0], a1 = di * acc0[1];
  float a2 = di * acc1[0], a3 = di * acc1[1];
  float a4 = di * acc2[0], a5 = di * acc2[1];
  float a6 = di * acc3[0], a7 = di * acc3[1];
  if (BIAS) {
    float4 b0 = *(const float4*)&bias[sl * 8];
    float4 b1v = *(const float4*)&bias[sl * 8 + 4];
    a0 += b0.x; a1 += b0.y; a2 += b0.z; a3 += b0.w;
    a4 += b1v.x; a5 += b1v.y; a6 += b1v.z; a7 += b1v.w;
  }
  if (g == 0) {
    if (OUTBF) {
      uint4 pk;
      pk.x = pack2bf(a0, a1); pk.y = pack2bf(a2, a3);
      pk.z = pack2bf(a4, a5); pk.w = pack2bf(a6, a7);
      *(uint4*)&((unsigned*)out)[(size_t)gw * 64 + sl * 4] = pk;
    } else {
      // next layer's table: pre-scale by dinv[d]
      uint2 pk;
      pk.x = fp8enc4(di * a0, di * a1, di * a2, di * a3);
      pk.y = fp8enc4(di * a4, di * a5, di * a6, di * a7);
      *(uint2*)&((unsigned*)out)[(size_t)gw * 32 + sl * 2] = pk;
    }
  }
}

// ---------------- GEMM2 (MFMA, 2x2 wave split) + epilogue ----------------

#define G2_ASTRIDE 272
#define G2_AOFF    (64 * G2_ASTRIDE)   // 17408
#define G2_BBYTES  32768

__global__ __launch_bounds__(256) void k_gemm2m(const unsigned short* __restrict__ Gb,
                                                const uint4* __restrict__ W23fv,
                                                const float* __restrict__ b2,
                                                const float* __restrict__ b3,
                                                const float* __restrict__ eps,
                                                float* __restrict__ z) {
  __shared__ char lds[G2_AOFF + G2_BBYTES];
  int tid  = threadIdx.x;
  int row0 = blockIdx.x * 64;
  int w    = tid >> 6;
  int wr   = w >> 1, wc = w & 1;
  int lane = tid & 63;

  {
    int ar = tid >> 2, aq = tid & 3;
    int row = row0 + ar;
    uint4 a0 = {}, a1 = {}, a2 = {}, a3 = {};
    if (row < NN) {
      const uint4* gp = (const uint4*)(Gb + (size_t)row * H1F) + aq * 4;
      a0 = gp[0]; a1 = gp[1]; a2 = gp[2]; a3 = gp[3];
    }
    char* Ab = lds + ar * G2_ASTRIDE + aq * 64;
    *(uint4*)(Ab)      = a0;
    *(uint4*)(Ab + 16) = a1;
    *(uint4*)(Ab + 32) = a2;
    *(uint4*)(Ab + 48) = a3;
  }
  {
    uint4* Bb = (uint4*)(lds + G2_AOFF);
#pragma unroll
    for (int j = 0; j < 8; ++j) Bb[tid + j * 256] = W23fv[tid + j * 256];
  }
  __syncthreads();

  f32x4 acc[2][4];
#pragma unroll
  for (int u = 0; u < 2; ++u)
#pragma unroll
    for (int f = 0; f < 4; ++f) acc[u][f] = (f32x4){0.f, 0.f, 0.f, 0.f};

#pragma unroll
  for (int s = 0; s < 4; ++s) {
    bf16x8 xa0 = *(const bf16x8*)(lds + (wr * 32 + (lane & 15)) * G2_ASTRIDE + s * 64 + (lane >> 4) * 16);
    bf16x8 xa1 = *(const bf16x8*)(lds + (wr * 32 + 16 + (lane & 15)) * G2_ASTRIDE + s * 64 + (lane >> 4) * 16);
#pragma unroll
    for (int f = 0; f < 4; ++f) {
      bf16x8 bt = *(const bf16x8*)(lds + G2_AOFF + ((s * 512 + (wc * 4 + f) * 64 + lane) << 4));
      acc[0][f] = __builtin_amdgcn_mfma_f32_16x16x32_bf16(bt, xa0, acc[0][f], 0, 0, 0);
      acc[1][f] = __builtin_amdgcn_mfma_f32_16x16x32_bf16(bt, xa1, acc[1][f], 0, 0, 0);
    }
  }

  int q = lane >> 4;
#pragma unroll
  for (int u = 0; u < 2; ++u) {
    int orow = row0 + wr * 32 + u * 16 + (lane & 15);
    if (orow < NN) {
      size_t base = (size_t)orow * 64;
#pragma unroll
      for (int f2 = 0; f2 < 2; ++f2) {
        int c = wc * 32 + f2 * 16 + q * 4;
        float4 ev = *(const float4*)&eps[base + c];
        f32x4 mu = acc[u][f2];
        f32x4 lv = acc[u][f2 + 2];
        float4 zo;
        zo.x = ev.x * __expf(lv[0] + b3[c + 0]) + mu[0] + b2[c + 0];
        zo.y = ev.y * __expf(lv[1] + b3[c + 1]) + mu[1] + b2[c + 1];
        zo.z = ev.z * __expf(lv[2] + b3[c + 2]) + mu[2] + b2[c + 2];
        zo.w = ev.w * __expf(lv[3] + b3[c + 3]) + mu[3] + b2[c + 3];
        *(float4*)&z[base + c] = zo;
      }
    }
  }
}

// ---------------- launch ----------------

extern "C" void kernel_launch(void* const* d_in, const int* in_sizes, int n_in,
                              void* d_out, int out_size, void* d_ws, size_t ws_size,
                              hipStream_t stream) {
  const float* x   = (const float*)d_in[0];
  const int*   ei  = (const int*)  d_in[1];
  const float* W1  = (const float*)d_in[2];
  const float* b1  = (const float*)d_in[3];
  const float* W2  = (const float*)d_in[4];
  const float* b2  = (const float*)d_in[5];
  const float* W3  = (const float*)d_in[6];
  const float* b3  = (const float*)d_in[7];
  const float* eps = (const float*)d_in[8];
  float* z = (float*)d_out;

  char* ws = (char*)d_ws;
  size_t o = 0;
  auto alloc = [&](size_t bytes) -> void* {
    void* p = ws + o;
    o = (o + bytes + 255) & ~(size_t)255;
    return p;
  };
  int*   gh     = (int*)  alloc((size_t)NBUK * NBIN * 4);
  int*   btot   = (int*)  alloc((size_t)NBUK * 4);
  int*   bbase  = (int*)  alloc((size_t)(NBUK + 1) * 4);
  int*   rowptr = (int*)  alloc((size_t)(NN + 1) * 4);
  float* dinv   = (float*)alloc((size_t)NN * 4);
  int*   csr    = (int*)  alloc((size_t)NE * 4);
  unsigned* tmp = (unsigned*)alloc((size_t)NE * 4);
  unsigned short* W1f  = (unsigned short*)alloc((size_t)16 * 8 * 64 * 8 * 2);  // 128KB
  unsigned short* W23f = (unsigned short*)alloc((size_t)4 * 8 * 64 * 8 * 2);   // 32KB
  unsigned* hw8 = (unsigned*)alloc((size_t)NN * 32 * 4);   // fp8 dinv*(x@W1)  [NN][128]
  unsigned* h8  = (unsigned*)alloc((size_t)NN * 32 * 4);   // fp8 dinv*h1      [NN][128]
  unsigned short* gb = (unsigned short*)alloc((size_t)NN * H1F * 2);  // bf16 Agg(h1)

  k_binhist<<<NBIN, 256, 0, stream>>>(ei, gh);
  k_rowscan<<<NBUK, 64, 0, stream>>>(gh, btot);
  k_bscan  <<<1, 512, 0, stream>>>(btot, bbase);
  k_binscat<<<NBIN, 256, 0, stream>>>(ei, gh, bbase, tmp);
  k_fill2x <<<NBUK, 256, 0, stream>>>(tmp, bbase, rowptr, dinv, csr);
  k_cvtw1f <<<32, 256, 0, stream>>>(W1, W1f);
  k_cvtw23f<<<8, 256, 0, stream>>>(W2, W3, W23f);

  k_gemm1m <<<(NN + 63) / 64, 256, 0, stream>>>(x, (const uint4*)W1f, dinv, hw8);
  k_agg8<true,  false><<<(NN * 64 + 255) / 256, 256, 0, stream>>>(hw8, rowptr, csr, dinv, b1, (void*)h8);
  k_agg8<false, true ><<<(NN * 64 + 255) / 256, 256, 0, stream>>>(h8,  rowptr, csr, dinv, nullptr, (void*)gb);
  k_gemm2m <<<(NN + 63) / 64, 256, 0, stream>>>(gb, (const uint4*)W23f, b2, b3, eps, z);
}

// Round 17
// 142.440 us; speedup vs baseline: 1.0315x; 1.0315x over previous
//
#include <hip/hip_runtime.h>
#include <math.h>

#define NN   50000
#define NE   1600000
#define FIN  512
#define H1F  128
#define NBUK  391    // ceil(NN/128)  — dst-bucket = 128 consecutive nodes
#define BIN_EPB 4096 // edges per binning block (16 per thread)
#define NBIN  391    // ceil(NE/BIN_EPB)

typedef __attribute__((ext_vector_type(8))) short bf16x8;
typedef __attribute__((ext_vector_type(4))) float f32x4;
typedef __attribute__((ext_vector_type(2))) float f32x2;

// ---------------- bf16 helpers ----------------
__device__ __forceinline__ float bflo(unsigned v) { return __uint_as_float(v << 16); }
__device__ __forceinline__ float bfhi(unsigned v) { return __uint_as_float(v & 0xffff0000u); }
__device__ __forceinline__ unsigned short f2bf(float f) {
  unsigned u = __float_as_uint(f);
  u += 0x7fffu + ((u >> 16) & 1u);   // round-to-nearest-even
  return (unsigned short)(u >> 16);
}
__device__ __forceinline__ unsigned pack2bf(float a, float b) {
  return (unsigned)f2bf(a) | ((unsigned)f2bf(b) << 16);
}

// ---------------- fp8 e4m3fn codec: HW cvt if available, SW fallback ----------------
#if defined(__has_builtin)
#  if __has_builtin(__builtin_amdgcn_cvt_pk_f32_fp8) && __has_builtin(__builtin_amdgcn_cvt_pk_fp8_f32)
#    define HW_FP8 1
#  endif
#endif
#ifndef HW_FP8
#  define HW_FP8 0
#endif

__device__ __forceinline__ float fp8dec_sw(unsigned v, int sh) {
  unsigned b = (v >> sh) & 0xffu;
  unsigned bits = ((b & 0x80u) << 24) | ((b & 0x7fu) << 20);
  return __uint_as_float(bits) * 0x1.0p+120f;
}
__device__ __forceinline__ unsigned fp8enc_sw(float f) {
  unsigned u = __float_as_uint(f * 0x1.0p-120f);
  unsigned s = (u >> 24) & 0x80u;
  u &= 0x7fffffffu;
  u += 0x7ffffu + ((u >> 20) & 1u);
  unsigned e = u >> 20;
  if (e > 0x7fu) e = 0x7fu;
  return s | e;
}

// decode 4 packed fp8 -> two f32x2 (feeds v_pk_add_f32 directly)
__device__ __forceinline__ void fp8dec4p(unsigned v, f32x2& lo, f32x2& hi) {
#if HW_FP8
  lo = __builtin_amdgcn_cvt_pk_f32_fp8(v, false);   // bytes 0,1
  hi = __builtin_amdgcn_cvt_pk_f32_fp8(v, true);    // bytes 2,3
#else
  lo = (f32x2){fp8dec_sw(v, 0), fp8dec_sw(v, 8)};
  hi = (f32x2){fp8dec_sw(v, 16), fp8dec_sw(v, 24)};
#endif
}
__device__ __forceinline__ unsigned fp8enc4(float a, float b, float c, float d) {
#if HW_FP8
  unsigned r = (unsigned)__builtin_amdgcn_cvt_pk_fp8_f32(a, b, 0, false);
  r = (unsigned)__builtin_amdgcn_cvt_pk_fp8_f32(c, d, (int)r, true);
  return r;
#else
  return fp8enc_sw(a) | (fp8enc_sw(b) << 8) | (fp8enc_sw(c) << 16) | (fp8enc_sw(d) << 24);
#endif
}

// ---------------- CSR build: radix partition, ZERO global atomics ----------------

__global__ __launch_bounds__(256) void k_binhist(const int* __restrict__ ei,
                                                 int* __restrict__ gh) {
  __shared__ int hist[NBUK];
  int t  = threadIdx.x;
  int e0 = blockIdx.x * BIN_EPB;
  for (int b = t; b < NBUK; b += 256) hist[b] = 0;
  __syncthreads();
#pragma unroll
  for (int j = 0; j < 16; ++j) {
    int e = e0 + j * 256 + t;
    if (e < NE) atomicAdd(&hist[ei[NE + e] >> 7], 1);
  }
  __syncthreads();
  for (int b = t; b < NBUK; b += 256) gh[(size_t)b * NBIN + blockIdx.x] = hist[b];
}

__global__ __launch_bounds__(64) void k_rowscan(int* __restrict__ gh,
                                                int* __restrict__ btot) {
  int row  = blockIdx.x;
  int lane = threadIdx.x;
  int* g = gh + (size_t)row * NBIN;
  int carry = 0;
  for (int c = 0; c < (NBIN + 63) / 64; ++c) {
    int idx = c * 64 + lane;
    int v = (idx < NBIN) ? g[idx] : 0;
    int incl = v;
#pragma unroll
    for (int off = 1; off < 64; off <<= 1) {
      int u = __shfl_up(incl, off, 64);
      if (lane >= off) incl += u;
    }
    if (idx < NBIN) g[idx] = carry + (incl - v);
    carry += __shfl(incl, 63, 64);
  }
  if (lane == 0) btot[row] = carry;
}

__global__ __launch_bounds__(512) void k_bscan(const int* __restrict__ btot,
                                               int* __restrict__ bbase) {
  __shared__ int ts[512];
  int t = threadIdx.x;
  int v = (t < NBUK) ? btot[t] : 0;
  ts[t] = v;
  __syncthreads();
  for (int off = 1; off < 512; off <<= 1) {
    int val = ts[t];
    int add = (t >= off) ? ts[t - off] : 0;
    __syncthreads();
    ts[t] = val + add;
    __syncthreads();
  }
  if (t < NBUK) bbase[t] = ts[t] - v;
  if (t == NBUK - 1) bbase[NBUK] = ts[t];   // == NE
}

__global__ __launch_bounds__(256) void k_binscat(const int* __restrict__ ei,
                                                 const int* __restrict__ gh,
                                                 const int* __restrict__ bbase,
                                                 unsigned* __restrict__ tmp) {
  __shared__ int hist[NBUK];
  __shared__ int sbase[NBUK];
  int t  = threadIdx.x;
  int e0 = blockIdx.x * BIN_EPB;
  for (int b = t; b < NBUK; b += 256) hist[b] = 0;
  __syncthreads();

  unsigned short d16[16];
  unsigned short p16[16];
#pragma unroll
  for (int j = 0; j < 16; ++j) {
    int e = e0 + j * 256 + t;
    d16[j] = 0xFFFFu;
    if (e < NE) {
      int d = ei[NE + e];
      d16[j] = (unsigned short)d;
      p16[j] = (unsigned short)atomicAdd(&hist[d >> 7], 1);
    }
  }
  __syncthreads();
  for (int b = t; b < NBUK; b += 256)
    sbase[b] = bbase[b] + gh[(size_t)b * NBIN + blockIdx.x];
  __syncthreads();
#pragma unroll
  for (int j = 0; j < 16; ++j) {
    int e = e0 + j * 256 + t;
    if (e < NE) {
      int s = ei[e];
      int d = (int)d16[j];
      tmp[sbase[d >> 7] + (int)p16[j]] = ((unsigned)s << 16) | (unsigned)d;
    }
  }
}

__global__ __launch_bounds__(256) void k_fill2x(const unsigned* __restrict__ tmp,
                                                const int* __restrict__ bbase,
                                                int* __restrict__ rowptr,
                                                float* __restrict__ dinv,
                                                int* __restrict__ csr) {
  __shared__ int cnt[128];
  __shared__ int lofs[128];
  __shared__ int cur[128];
  __shared__ int ts[256];
  int b  = blockIdx.x;
  int t  = threadIdx.x;
  int n0 = b << 7;
  int beg = bbase[b];
  int end = bbase[b + 1];
  if (t < 128) { cnt[t] = 0; cur[t] = 0; }
  __syncthreads();
  for (int i = beg + t; i < end; i += 256)
    atomicAdd(&cnt[tmp[i] & 127u], 1);   // d - n0 == d & 127
  __syncthreads();
  int v = (t < 128) ? cnt[t] : 0;
  ts[t] = v;
  __syncthreads();
  for (int off = 1; off < 128; off <<= 1) {
    int val = ts[t];
    int add = (t >= off) ? ts[t - off] : 0;
    __syncthreads();
    ts[t] = val + add;
    __syncthreads();
  }
  if (t < 128) {
    int excl = ts[t] - v;
    lofs[t] = beg + excl;
    int n = n0 + t;
    if (n < NN) {
      rowptr[n] = beg + excl;
      dinv[n]   = rsqrtf((float)(v + 1));   // self-loop included
    }
  }
  if (b == NBUK - 1 && t == 0) rowptr[NN] = end;
  __syncthreads();
  for (int i = beg + t; i < end; i += 256) {
    unsigned pk = tmp[i];
    int dl = (int)(pk & 127u);
    int s  = (int)(pk >> 16);
    int p  = atomicAdd(&cur[dl], 1);
    csr[lofs[dl] + p] = s;
  }
}

// ---------------- weight repack: fragment-order bf16 ----------------

__global__ __launch_bounds__(256) void k_cvtw1f(const float* __restrict__ W,
                                                unsigned short* __restrict__ W1f) {
  int i = blockIdx.x * 256 + threadIdx.x;   // 8192 chunks
  if (i >= 16 * 8 * 64) return;
  int s = i >> 9, rem = i & 511, f = rem >> 6, lane = rem & 63;
  int row = f * 16 + (lane & 15);
  int kb  = s * 32 + (lane >> 4) * 8;
  unsigned short c8[8];
#pragma unroll
  for (int j = 0; j < 8; ++j) c8[j] = f2bf(W[(size_t)(kb + j) * H1F + row]);
  *(uint4*)&W1f[(size_t)i * 8] = *(uint4*)c8;
}

// W23f interleaved for 2x2 wave split: col-block pairs [W2lo, W3lo, W2hi, W3hi].
__global__ __launch_bounds__(256) void k_cvtw23f(const float* __restrict__ W2,
                                                 const float* __restrict__ W3,
                                                 unsigned short* __restrict__ Wf) {
  int i = blockIdx.x * 256 + threadIdx.x;   // 2048 chunks
  if (i >= 4 * 8 * 64) return;
  int s = i >> 9, rem = i & 511, f = rem >> 6, lane = rem & 63;
  int row = f * 16 + (lane & 15);
  int kb  = s * 32 + (lane >> 4) * 8;
  int pair = row >> 5;
  const float* Wsrc = (pair & 1) ? W3 : W2;
  int c = (pair >> 1) * 32 + (row & 31);
  unsigned short c8[8];
#pragma unroll
  for (int j = 0; j < 8; ++j) c8[j] = f2bf(Wsrc[(size_t)(kb + j) * 64 + c]);
  *(uint4*)&Wf[(size_t)i * 8] = *(uint4*)c8;
}

// ---------------- GEMM1 (MFMA, 2x2 wave split): table1 = fp8(dinv * (x @ W1)) ----------------

#define G1_ABUF 5120                  // 64 rows * 80B
#define G1_BBUF 8192                  // 512 chunks * 16B
#define G1_BUF  (G1_ABUF + G1_BBUF)
#define G1_NSTEP 16

__global__ __launch_bounds__(256) void k_gemm1m(const float* __restrict__ X,
                                                const uint4* __restrict__ W1fv,
                                                const float* __restrict__ dinv,
                                                unsigned* __restrict__ out8) {
  __shared__ char lds[2 * G1_BUF];
  int tid  = threadIdx.x;
  int row0 = blockIdx.x * 64;
  int w    = tid >> 6;
  int wr   = w >> 1, wc = w & 1;
  int lane = tid & 63;

  int ar = tid >> 2, aq = tid & 3;        // A: row ar, k-chunk aq (8 floats)

  float4 av0, av1;
  uint4  bu0, bu1;

  auto load_g = [&](int s) {
    int k0 = s * 32;
    int row = row0 + ar;
    av0 = make_float4(0.f, 0.f, 0.f, 0.f);
    av1 = av0;
    if (row < NN) {
      const float* gp = X + (size_t)row * FIN + k0 + aq * 8;
      av0 = *(const float4*)gp;
      av1 = *(const float4*)(gp + 4);
    }
    const uint4* bp = W1fv + (size_t)s * 512;
    bu0 = bp[tid];
    bu1 = bp[tid + 256];
  };
  auto store_l = [&](int buf) {
    char* Ab = lds + buf * G1_BUF;
    char* Bb = Ab + G1_ABUF;
    uint4 ap;
    ap.x = pack2bf(av0.x, av0.y); ap.y = pack2bf(av0.z, av0.w);
    ap.z = pack2bf(av1.x, av1.y); ap.w = pack2bf(av1.z, av1.w);
    *(uint4*)(Ab + ar * 80 + aq * 16) = ap;
    *(uint4*)(Bb + tid * 16)        = bu0;   // linear -> conflict-free
    *(uint4*)(Bb + tid * 16 + 4096) = bu1;
  };

  f32x4 acc[2][4];
#pragma unroll
  for (int u = 0; u < 2; ++u)
#pragma unroll
    for (int f = 0; f < 4; ++f) acc[u][f] = (f32x4){0.f, 0.f, 0.f, 0.f};

  load_g(0);
  store_l(0);

  for (int s = 0; s < G1_NSTEP; ++s) {
    if (s + 1 < G1_NSTEP) load_g(s + 1);
    __syncthreads();
    const char* Ab = lds + (s & 1) * G1_BUF;
    const char* Bb = Ab + G1_ABUF;
    bf16x8 xa0 = *(const bf16x8*)(Ab + (wr * 32 + (lane & 15)) * 80 + (lane >> 4) * 16);
    bf16x8 xa1 = *(const bf16x8*)(Ab + (wr * 32 + 16 + (lane & 15)) * 80 + (lane >> 4) * 16);
#pragma unroll
    for (int f = 0; f < 4; ++f) {
      bf16x8 bt = *(const bf16x8*)(Bb + (wc * 4 + f) * 1024 + lane * 16);
      acc[0][f] = __builtin_amdgcn_mfma_f32_16x16x32_bf16(bt, xa0, acc[0][f], 0, 0, 0);
      acc[1][f] = __builtin_amdgcn_mfma_f32_16x16x32_bf16(bt, xa1, acc[1][f], 0, 0, 0);
    }
    if (s + 1 < G1_NSTEP) store_l((s + 1) & 1);
  }

#pragma unroll
  for (int u = 0; u < 2; ++u) {
    int orow = row0 + wr * 32 + u * 16 + (lane & 15);
    if (orow < NN) {
      float di = dinv[orow];                // pre-scale: table1 = dinv * hw1
      size_t base = (size_t)orow * 32;      // 32 uints = 128 fp8 per row
#pragma unroll
      for (int f = 0; f < 4; ++f) {
        int col = (wc * 4 + f) * 16 + (lane >> 4) * 4;
        out8[base + (col >> 2)] = fp8enc4(di * acc[u][f][0], di * acc[u][f][1],
                                          di * acc[u][f][2], di * acc[u][f][3]);
      }
    }
  }
}

// ---------------- aggregation over PRE-SCALED fp8 table ----------------
// 32-lane group per dst node; lane holds 4 feats (1 uint = 128B row gather).
// 8-deep register pipeline; per edge: 1 shfl + 1 load + 2 cvt + 2 pk_add.
// table[s] = dinv[s]*h[s]; out[d] = dinv[d]*(Σ table[s] + table[d]) (+bias)
// All __shfl executed wave-uniformly (R14 lesson: EXEC-masked shfl source UB).

template<bool BIAS, bool OUTBF>
__global__ __launch_bounds__(256) void k_agg8(const unsigned* __restrict__ feat,   // [NN][32] uints
                                              const int* __restrict__ rowptr,
                                              const int* __restrict__ csr,
                                              const float* __restrict__ dinv,
                                              const float* __restrict__ bias,
                                              void* __restrict__ out) {
  int gw   = (blockIdx.x * 256 + threadIdx.x) >> 5;   // dst node
  int lane = threadIdx.x & 31;
  if (gw >= NN) return;
  int beg = rowptr[gw], end = rowptr[gw + 1];
  float di = dinv[gw];
  f32x2 aA = (f32x2){0.f, 0.f}, bA = (f32x2){0.f, 0.f};
  f32x2 aB = (f32x2){0.f, 0.f}, bB = (f32x2){0.f, 0.f};

  for (int e = beg; e < end; e += 32) {
    int cnt = end - e; if (cnt > 32) cnt = 32;
    int sv = 0;
    if (lane < cnt) sv = csr[e + lane];
    int j = 0;
    for (; j + 8 <= cnt; j += 8) {
      unsigned vv[8];
#pragma unroll
      for (int q = 0; q < 8; ++q) {
        int s = __shfl(sv, j + q, 32);
        vv[q] = feat[(size_t)s * 32 + lane];
      }
#pragma unroll
      for (int q = 0; q < 8; ++q) {
        f32x2 lo, hi;
        fp8dec4p(vv[q], lo, hi);
        if (q & 1) { aB += lo; bB += hi; }
        else       { aA += lo; bA += hi; }
      }
    }
    for (; j < cnt; ++j) {
      int s = __shfl(sv, j, 32);
      f32x2 lo, hi;
      fp8dec4p(feat[(size_t)s * 32 + lane], lo, hi);
      aA += lo; bA += hi;
    }
  }
  // self loop: table[d] is already dinv[d]*h[d]
  {
    f32x2 lo, hi;
    fp8dec4p(feat[(size_t)gw * 32 + lane], lo, hi);
    aA += lo; bA += hi;
  }
  f32x2 s01 = aA + aB;
  f32x2 s23 = bA + bB;
  float a0 = di * s01[0], a1 = di * s01[1];
  float a2 = di * s23[0], a3 = di * s23[1];
  if (BIAS) {
    float4 bb = *(const float4*)&bias[lane * 4];
    a0 += bb.x; a1 += bb.y; a2 += bb.z; a3 += bb.w;
  }
  if (OUTBF) {
    uint2 pk; pk.x = pack2bf(a0, a1); pk.y = pack2bf(a2, a3);
    *(uint2*)&((unsigned*)out)[(size_t)gw * 64 + lane * 2] = pk;
  } else {
    // next layer's table: pre-scale by dinv[d]
    ((unsigned*)out)[(size_t)gw * 32 + lane] = fp8enc4(di * a0, di * a1, di * a2, di * a3);
  }
}

// ---------------- GEMM2 (MFMA, 2x2 wave split) + epilogue ----------------
// B packed as col-block pairs [W2lo, W3lo, W2hi, W3hi]: wave wc owns z-cols
// wc*32..wc*32+31 with acc[u][0..1]=mu, acc[u][2..3]=lv (wave-local pairs).

#define G2_ASTRIDE 272
#define G2_AOFF    (64 * G2_ASTRIDE)   // 17408
#define G2_BBYTES  32768

__global__ __launch_bounds__(256) void k_gemm2m(const unsigned short* __restrict__ Gb,
                                                const uint4* __restrict__ W23fv,
                                                const float* __restrict__ b2,
                                                const float* __restrict__ b3,
                                                const float* __restrict__ eps,
                                                float* __restrict__ z) {
  __shared__ char lds[G2_AOFF + G2_BBYTES];
  int tid  = threadIdx.x;
  int row0 = blockIdx.x * 64;
  int w    = tid >> 6;
  int wr   = w >> 1, wc = w & 1;
  int lane = tid & 63;

  {
    int ar = tid >> 2, aq = tid & 3;
    int row = row0 + ar;
    uint4 a0 = {}, a1 = {}, a2 = {}, a3 = {};
    if (row < NN) {
      const uint4* gp = (const uint4*)(Gb + (size_t)row * H1F) + aq * 4;
      a0 = gp[0]; a1 = gp[1]; a2 = gp[2]; a3 = gp[3];
    }
    char* Ab = lds + ar * G2_ASTRIDE + aq * 64;
    *(uint4*)(Ab)      = a0;
    *(uint4*)(Ab + 16) = a1;
    *(uint4*)(Ab + 32) = a2;
    *(uint4*)(Ab + 48) = a3;
  }
  {
    uint4* Bb = (uint4*)(lds + G2_AOFF);
#pragma unroll
    for (int j = 0; j < 8; ++j) Bb[tid + j * 256] = W23fv[tid + j * 256];
  }
  __syncthreads();

  f32x4 acc[2][4];
#pragma unroll
  for (int u = 0; u < 2; ++u)
#pragma unroll
    for (int f = 0; f < 4; ++f) acc[u][f] = (f32x4){0.f, 0.f, 0.f, 0.f};

#pragma unroll
  for (int s = 0; s < 4; ++s) {
    bf16x8 xa0 = *(const bf16x8*)(lds + (wr * 32 + (lane & 15)) * G2_ASTRIDE + s * 64 + (lane >> 4) * 16);
    bf16x8 xa1 = *(const bf16x8*)(lds + (wr * 32 + 16 + (lane & 15)) * G2_ASTRIDE + s * 64 + (lane >> 4) * 16);
#pragma unroll
    for (int f = 0; f < 4; ++f) {
      bf16x8 bt = *(const bf16x8*)(lds + G2_AOFF + ((s * 512 + (wc * 4 + f) * 64 + lane) << 4));
      acc[0][f] = __builtin_amdgcn_mfma_f32_16x16x32_bf16(bt, xa0, acc[0][f], 0, 0, 0);
      acc[1][f] = __builtin_amdgcn_mfma_f32_16x16x32_bf16(bt, xa1, acc[1][f], 0, 0, 0);
    }
  }

  int q = lane >> 4;
#pragma unroll
  for (int u = 0; u < 2; ++u) {
    int orow = row0 + wr * 32 + u * 16 + (lane & 15);
    if (orow < NN) {
      size_t base = (size_t)orow * 64;
#pragma unroll
      for (int f2 = 0; f2 < 2; ++f2) {
        int c = wc * 32 + f2 * 16 + q * 4;
        float4 ev = *(const float4*)&eps[base + c];
        f32x4 mu = acc[u][f2];
        f32x4 lv = acc[u][f2 + 2];
        float4 zo;
        zo.x = ev.x * __expf(lv[0] + b3[c + 0]) + mu[0] + b2[c + 0];
        zo.y = ev.y * __expf(lv[1] + b3[c + 1]) + mu[1] + b2[c + 1];
        zo.z = ev.z * __expf(lv[2] + b3[c + 2]) + mu[2] + b2[c + 2];
        zo.w = ev.w * __expf(lv[3] + b3[c + 3]) + mu[3] + b2[c + 3];
        *(float4*)&z[base + c] = zo;
      }
    }
  }
}

// ---------------- launch ----------------

extern "C" void kernel_launch(void* const* d_in, const int* in_sizes, int n_in,
                              void* d_out, int out_size, void* d_ws, size_t ws_size,
                              hipStream_t stream) {
  const float* x   = (const float*)d_in[0];
  const int*   ei  = (const int*)  d_in[1];
  const float* W1  = (const float*)d_in[2];
  const float* b1  = (const float*)d_in[3];
  const float* W2  = (const float*)d_in[4];
  const float* b2  = (const float*)d_in[5];
  const float* W3  = (const float*)d_in[6];
  const float* b3  = (const float*)d_in[7];
  const float* eps = (const float*)d_in[8];
  float* z = (float*)d_out;

  char* ws = (char*)d_ws;
  size_t o = 0;
  auto alloc = [&](size_t bytes) -> void* {
    void* p = ws + o;
    o = (o + bytes + 255) & ~(size_t)255;
    return p;
  };
  int*   gh     = (int*)  alloc((size_t)NBUK * NBIN * 4);
  int*   btot   = (int*)  alloc((size_t)NBUK * 4);
  int*   bbase  = (int*)  alloc((size_t)(NBUK + 1) * 4);
  int*   rowptr = (int*)  alloc((size_t)(NN + 1) * 4);
  float* dinv   = (float*)alloc((size_t)NN * 4);
  int*   csr    = (int*)  alloc((size_t)NE * 4);
  unsigned* tmp = (unsigned*)alloc((size_t)NE * 4);
  unsigned short* W1f  = (unsigned short*)alloc((size_t)16 * 8 * 64 * 8 * 2);  // 128KB
  unsigned short* W23f = (unsigned short*)alloc((size_t)4 * 8 * 64 * 8 * 2);   // 32KB
  unsigned* hw8 = (unsigned*)alloc((size_t)NN * 32 * 4);   // fp8 dinv*(x@W1)  [NN][128]
  unsigned* h8  = (unsigned*)alloc((size_t)NN * 32 * 4);   // fp8 dinv*h1      [NN][128]
  unsigned short* gb = (unsigned short*)alloc((size_t)NN * H1F * 2);  // bf16 Agg(h1)

  k_binhist<<<NBIN, 256, 0, stream>>>(ei, gh);
  k_rowscan<<<NBUK, 64, 0, stream>>>(gh, btot);
  k_bscan  <<<1, 512, 0, stream>>>(btot, bbase);
  k_binscat<<<NBIN, 256, 0, stream>>>(ei, gh, bbase, tmp);
  k_fill2x <<<NBUK, 256, 0, stream>>>(tmp, bbase, rowptr, dinv, csr);
  k_cvtw1f <<<32, 256, 0, stream>>>(W1, W1f);
  k_cvtw23f<<<8, 256, 0, stream>>>(W2, W3, W23f);

  k_gemm1m <<<(NN + 63) / 64, 256, 0, stream>>>(x, (const uint4*)W1f, dinv, hw8);
  k_agg8<true,  false><<<(NN * 32 + 255) / 256, 256, 0, stream>>>(hw8, rowptr, csr, dinv, b1, (void*)h8);
  k_agg8<false, true ><<<(NN * 32 + 255) / 256, 256, 0, stream>>>(h8,  rowptr, csr, dinv, nullptr, (void*)gb);
  k_gemm2m <<<(NN + 63) / 64, 256, 0, stream>>>(gb, (const uint4*)W23f, b2, b3, eps, z);
}